// Round 9
// baseline (132.750 us; speedup 1.0000x reference)
//
#include <hip/hip_runtime.h>
#include <hip/hip_fp16.h>

#define N_ROWS 8192
#define D_IN   4096
#define D_F    8192

// Radix-4 Hadamard butterfly over two index bits (f32).
__device__ __forceinline__ void h4(float& a, float& b, float& c, float& d) {
  float t0 = a + b, t1 = a - b, t2 = c + d, t3 = c - d;
  a = t0 + t2; c = t0 - t2;
  b = t1 + t3; d = t1 - t3;
}

// DPP move: result lane gets source lane per CTRL (quad_perm / row ops).
template<int CTRL>
__device__ __forceinline__ float dppf(float v) {
  int iv = __builtin_bit_cast(int, v);
  int r = __builtin_amdgcn_update_dpp(0, iv, CTRL, 0xF, 0xF, true);
  return __builtin_bit_cast(float, r);
}

#define DPP_QUAD_XOR1       0xB1   // quad_perm(1,0,3,2)
#define DPP_QUAD_XOR2       0x4E   // quad_perm(2,3,0,1)
#define DPP_QUAD_XOR3       0x1B   // quad_perm(3,2,1,0)
#define DPP_ROW_HALF_MIRROR 0x141  // XOR 7 within 16-lane row
#define DPP_ROW_ROR8        0x128  // rotate 8 within row == XOR 8

__device__ __forceinline__ unsigned pkrtz(float lo, float hi) {
#if __has_builtin(__builtin_amdgcn_cvt_pkrtz)
  auto h = __builtin_amdgcn_cvt_pkrtz(lo, hi);   // __fp16 ext_vector(2)
  return __builtin_bit_cast(unsigned, h);
#else
  __half2 h = __floats2half2_rn(lo, hi);
  return __builtin_bit_cast(unsigned, h);
#endif
}
__device__ __forceinline__ float2 upk(unsigned u) {
  return __half22float2(__builtin_bit_cast(__half2, u));
}
// packed f16x2 add/sub on u32 bit patterns (v_pk_add_f16 / v_pk_sub_f16)
__device__ __forceinline__ unsigned padd(unsigned a, unsigned b) {
  __half2 r = __hadd2(__builtin_bit_cast(__half2, a), __builtin_bit_cast(__half2, b));
  return __builtin_bit_cast(unsigned, r);
}
__device__ __forceinline__ unsigned psub(unsigned a, unsigned b) {
  __half2 r = __hsub2(__builtin_bit_cast(__half2, a), __builtin_bit_cast(__half2, b));
  return __builtin_bit_cast(unsigned, r);
}

struct Sg { float s0, s1, s2, s3, s4, s5; };

// FWHT of one row over bits {0,1} (reg h4), {11} (reg h2), {2..7}
// (DPP/permlane VALU cross-lane). 8 fp32 out in v[2][4].
// Bits {8,9,10} (wave bits) are left for the LDS trip.
__device__ __forceinline__ void fwht_row8(const float4* __restrict__ xrow,
                                          const float4 rv[2],
                                          int t, int lane, const Sg& sg,
                                          float v[2][4]) {
  #pragma unroll
  for (int c = 0; c < 2; ++c) {
    float4 tv = xrow[c * 512 + t];
    v[c][0] = tv.x * rv[c].x;
    v[c][1] = tv.y * rv[c].y;
    v[c][2] = tv.z * rv[c].z;
    v[c][3] = tv.w * rv[c].w;
  }
  // bits {0,1}
  h4(v[0][0], v[0][1], v[0][2], v[0][3]);
  h4(v[1][0], v[1][1], v[1][2], v[1][3]);
  // bit {11}
  #pragma unroll
  for (int i = 0; i < 4; ++i) {
    float a = v[0][i], b = v[1][i];
    v[0][i] = a + b; v[1][i] = a - b;
  }

  #pragma unroll
  for (int c = 0; c < 2; ++c)
    #pragma unroll
    for (int i = 0; i < 4; ++i) {     // XOR 1 (e-bit 2)
      float p = dppf<DPP_QUAD_XOR1>(v[c][i]);
      v[c][i] = fmaf(sg.s0, v[c][i], p);
    }
  #pragma unroll
  for (int c = 0; c < 2; ++c)
    #pragma unroll
    for (int i = 0; i < 4; ++i) {     // XOR 2 (e-bit 3)
      float p = dppf<DPP_QUAD_XOR2>(v[c][i]);
      v[c][i] = fmaf(sg.s1, v[c][i], p);
    }
  #pragma unroll
  for (int c = 0; c < 2; ++c)
    #pragma unroll
    for (int i = 0; i < 4; ++i) {     // XOR 4 (e-bit 4): XOR7 then XOR3
      float p = dppf<DPP_QUAD_XOR3>(dppf<DPP_ROW_HALF_MIRROR>(v[c][i]));
      v[c][i] = fmaf(sg.s2, v[c][i], p);
    }
  #pragma unroll
  for (int c = 0; c < 2; ++c)
    #pragma unroll
    for (int i = 0; i < 4; ++i) {     // XOR 8 (e-bit 5)
      float p = dppf<DPP_ROW_ROR8>(v[c][i]);
      v[c][i] = fmaf(sg.s3, v[c][i], p);
    }
  #pragma unroll
  for (int c = 0; c < 2; ++c)
    #pragma unroll
    for (int i = 0; i < 4; ++i) {     // XOR 16 (e-bit 6)
#if __has_builtin(__builtin_amdgcn_permlane16_swap)
      unsigned iv = __builtin_bit_cast(unsigned, v[c][i]);
      auto r = __builtin_amdgcn_permlane16_swap(iv, iv, false, false);
      float p = __builtin_bit_cast(float, (lane & 16) ? r[0] : r[1]);
#else
      float p = __shfl_xor(v[c][i], 16, 64);
#endif
      v[c][i] = fmaf(sg.s4, v[c][i], p);
    }
  #pragma unroll
  for (int c = 0; c < 2; ++c)
    #pragma unroll
    for (int i = 0; i < 4; ++i) {     // XOR 32 (e-bit 7)
#if __has_builtin(__builtin_amdgcn_permlane32_swap)
      unsigned iv = __builtin_bit_cast(unsigned, v[c][i]);
      auto r = __builtin_amdgcn_permlane32_swap(iv, iv, false, false);
      float p = __builtin_bit_cast(float, (lane & 32) ? r[0] : r[1]);
#else
      float p = __shfl_xor(v[c][i], 32, 64);
#endif
      v[c][i] = fmaf(sg.s5, v[c][i], p);
    }
}

// One degree, straight-line. zp: packed u32 = (f16 row1)<<16 | (f16 row0).
// Row0 is packed to f16 pairs immediately (its f32 regs die) before row1.
__device__ __forceinline__ void degree_step(
    int d, int t, int lane, const Sg& sg,
    const float4* __restrict__ x0, const float4* __restrict__ x1,
    const float* __restrict__ rad, const int* __restrict__ perm,
    unsigned* __restrict__ zp, float acc0[16], float acc1[16]) {
  const float4* rrow = reinterpret_cast<const float4*>(rad) + d * (D_IN / 4);
  uint4* z4 = reinterpret_cast<uint4*>(zp);

  // rad loaded ONCE per degree, shared by both rows
  float4 rv[2];
  rv[0] = rrow[t];
  rv[1] = rrow[512 + t];

  unsigned P0[4];
  {
    float v[2][4];
    fwht_row8(x0, rv, t, lane, sg, v);
    P0[0] = pkrtz(v[0][0], v[0][1]);
    P0[1] = pkrtz(v[0][2], v[0][3]);
    P0[2] = pkrtz(v[1][0], v[1][1]);
    P0[3] = pkrtz(v[1][2], v[1][3]);
  }
  float v1[2][4];
  fwht_row8(x1, rv, t, lane, sg, v1);

  __syncthreads();   // previous degree's gather has finished reading zp

  // merge rows byte-wise (v_perm) and stage, natural-layout b128
  #pragma unroll
  for (int c = 0; c < 2; ++c) {
    unsigned Qa = pkrtz(v1[c][0], v1[c][1]);
    unsigned Qb = pkrtz(v1[c][2], v1[c][3]);
    uint4 u;
    u.x = __builtin_amdgcn_perm(Qa, P0[2*c],   0x05040100u);
    u.y = __builtin_amdgcn_perm(Qa, P0[2*c],   0x07060302u);
    u.z = __builtin_amdgcn_perm(Qb, P0[2*c+1], 0x05040100u);
    u.w = __builtin_amdgcn_perm(Qb, P0[2*c+1], 0x07060302u);
    z4[c * 512 + t] = u;
  }
  __syncthreads();

  // trip: wave bits {8,9,10}, radix-8, ENTIRELY in packed f16 arithmetic.
  // Thread owns one 8-group: pe(w) = base + w*256 where
  // base = c'*2048 + l'*4 + i' = ((t&0x100)<<3) | (t&0xFF).
  // Bank check: base%32 = (t&0xFF)%32 -> 2 lanes/bank, conflict-free.
  {
    const int base = ((t & 0x100) << 3) | (t & 0xFF);
    unsigned q[8];
    #pragma unroll
    for (int w = 0; w < 8; ++w) q[w] = zp[base + w * 256];
    #pragma unroll
    for (int s = 1; s < 8; s <<= 1)
      #pragma unroll
      for (int w = 0; w < 8; ++w)
        if (!(w & s)) {
          unsigned a = q[w], b = q[w | s];
          q[w] = padd(a, b);
          q[w | s] = psub(a, b);
        }
    #pragma unroll
    for (int w = 0; w < 8; ++w) zp[base + w * 256] = q[w];
  }
  __syncthreads();

  // packed gather: one u32 read serves both rows
  const int4* p4 = reinterpret_cast<const int4*>(perm) + d * (D_F / 4);
  #pragma unroll
  for (int it = 0; it < 4; ++it) {
    int4 p = p4[it * 512 + t];
    float2 g0 = upk(zp[p.x]);
    float2 g1 = upk(zp[p.y]);
    float2 g2 = upk(zp[p.z]);
    float2 g3 = upk(zp[p.w]);
    acc0[it*4+0] *= g0.x; acc1[it*4+0] *= g0.y;
    acc0[it*4+1] *= g1.x; acc1[it*4+1] *= g1.y;
    acc0[it*4+2] *= g2.x; acc1[it*4+2] *= g2.y;
    acc0[it*4+3] *= g3.x; acc1[it*4+3] *= g3.y;
  }
}

// One block = TWO rows, 512 threads (8 waves). Small per-thread footprint:
// acc 32 f32, fwht state 8 f32/row -> VGPR ~70, high residency.
__global__ __launch_bounds__(512) void srht_kernel(
    const float* __restrict__ x,
    const float* __restrict__ rad,
    const int* __restrict__ perm,
    float* __restrict__ out)
{
  __shared__ __align__(16) unsigned zp[D_IN];   // 16 KiB packed f16x2
  const int t    = threadIdx.x;
  const int lane = t & 63;
  const int n0   = blockIdx.x * 2;

  Sg sg;
  sg.s0 = (lane & 1)  ? -1.f : 1.f;
  sg.s1 = (lane & 2)  ? -1.f : 1.f;
  sg.s2 = (lane & 4)  ? -1.f : 1.f;
  sg.s3 = (lane & 8)  ? -1.f : 1.f;
  sg.s4 = (lane & 16) ? -1.f : 1.f;
  sg.s5 = (lane & 32) ? -1.f : 1.f;

  const float INV = 0.01104854345603981f;  // 1/sqrt(8192)
  float acc0[16], acc1[16];
  #pragma unroll
  for (int k = 0; k < 16; ++k) { acc0[k] = INV; acc1[k] = INV; }

  const float4* x0 = reinterpret_cast<const float4*>(x) + (size_t)n0 * (D_IN / 4);
  const float4* x1 = x0 + (D_IN / 4);

  degree_step(0, t, lane, sg, x0, x1, rad, perm, zp, acc0, acc1);
  degree_step(1, t, lane, sg, x0, x1, rad, perm, zp, acc0, acc1);
  degree_step(2, t, lane, sg, x0, x1, rad, perm, zp, acc0, acc1);

  // coalesced float4 output, two rows
  float4* oa = reinterpret_cast<float4*>(out + (size_t)n0 * D_F);
  float4* ob = reinterpret_cast<float4*>(out + (size_t)(n0 + 1) * D_F);
  #pragma unroll
  for (int it = 0; it < 4; ++it) {
    oa[it * 512 + t] =
        make_float4(acc0[it*4+0], acc0[it*4+1], acc0[it*4+2], acc0[it*4+3]);
    ob[it * 512 + t] =
        make_float4(acc1[it*4+0], acc1[it*4+1], acc1[it*4+2], acc1[it*4+3]);
  }
}

extern "C" void kernel_launch(void* const* d_in, const int* in_sizes, int n_in,
                              void* d_out, int out_size, void* d_ws, size_t ws_size,
                              hipStream_t stream) {
  const float* x   = (const float*)d_in[0];
  const float* rad = (const float*)d_in[1];
  const int* perm  = (const int*)d_in[2];
  float* out       = (float*)d_out;
  srht_kernel<<<N_ROWS / 2, 512, 0, stream>>>(x, rad, perm, out);
}

// Round 10
// 92.005 us; speedup vs baseline: 1.4429x; 1.4429x over previous
//
#include <hip/hip_runtime.h>
#include <hip/hip_fp16.h>

#define N_ROWS 8192
#define D_IN   4096
#define D_F    8192

// DPP move on a packed u32: result lane gets source lane per CTRL.
template<int CTRL>
__device__ __forceinline__ unsigned dppu(unsigned v) {
  int r = __builtin_amdgcn_update_dpp(0, (int)v, CTRL, 0xF, 0xF, true);
  return (unsigned)r;
}

#define DPP_QUAD_XOR1       0xB1   // quad_perm(1,0,3,2)
#define DPP_QUAD_XOR2       0x4E   // quad_perm(2,3,0,1)
#define DPP_QUAD_XOR3       0x1B   // quad_perm(3,2,1,0)
#define DPP_ROW_HALF_MIRROR 0x141  // XOR 7 within 16-lane row
#define DPP_ROW_ROR8        0x128  // rotate 8 within row == XOR 8

__device__ __forceinline__ unsigned pkrtz(float lo, float hi) {
#if __has_builtin(__builtin_amdgcn_cvt_pkrtz)
  auto h = __builtin_amdgcn_cvt_pkrtz(lo, hi);   // __fp16 ext_vector(2)
  return __builtin_bit_cast(unsigned, h);
#else
  __half2 h = __floats2half2_rn(lo, hi);
  return __builtin_bit_cast(unsigned, h);
#endif
}
__device__ __forceinline__ float2 upk(unsigned u) {
  return __half22float2(__builtin_bit_cast(__half2, u));
}
// packed f16x2 math on u32 bit patterns (v_pk_add/sub/mul/fma_f16, RNE)
__device__ __forceinline__ unsigned padd(unsigned a, unsigned b) {
  return __builtin_bit_cast(unsigned,
      __hadd2(__builtin_bit_cast(__half2, a), __builtin_bit_cast(__half2, b)));
}
__device__ __forceinline__ unsigned psub(unsigned a, unsigned b) {
  return __builtin_bit_cast(unsigned,
      __hsub2(__builtin_bit_cast(__half2, a), __builtin_bit_cast(__half2, b)));
}
__device__ __forceinline__ unsigned pmul(unsigned a, unsigned b) {
  return __builtin_bit_cast(unsigned,
      __hmul2(__builtin_bit_cast(__half2, a), __builtin_bit_cast(__half2, b)));
}
__device__ __forceinline__ unsigned pfma(unsigned a, unsigned b, unsigned c) {
  return __builtin_bit_cast(unsigned,
      __hfma2(__builtin_bit_cast(__half2, a), __builtin_bit_cast(__half2, b),
              __builtin_bit_cast(__half2, c)));
}
// packed radix-4 Hadamard butterfly
__device__ __forceinline__ void h4p(unsigned& a, unsigned& b,
                                    unsigned& c, unsigned& d) {
  unsigned t0 = padd(a, b), t1 = psub(a, b), t2 = padd(c, d), t3 = psub(c, d);
  a = padd(t0, t2); c = psub(t0, t2);
  b = padd(t1, t3); d = psub(t1, t3);
}

// One block = TWO rows packed as f16x2 in one u32 per element, END TO END.
// elem e = c*1024 + t*4 + i: i=e[1:0], lane=e[7:2], wv=e[9:8], c=e[11:10]
//  - bits {0,1},{10,11}: packed h4p in registers
//  - bits {2..7}: packed DPP / permlane lane stages (v_pk_fma_f16)
//  - bits {8,9}: packed b128 LDS RMW trip (R8's verified conflict-free pattern)
// x is pre-scaled by s = cbrt(1/sqrt(8192)) and packed ONCE (held in regs
// across degrees); rad=+-1 multiplies are EXACT in f16; acc is packed f16
// initialized to 0.25 so |out|/4 <= 32512 stays in f16 range (x4 at store).
__global__ __launch_bounds__(256) void srht_kernel(
    const float* __restrict__ x,
    const float* __restrict__ rad,
    const int* __restrict__ perm,
    float* __restrict__ out)
{
  __shared__ __align__(16) unsigned zp[D_IN];   // 16 KiB packed f16x2
  const int t    = threadIdx.x;
  const int lane = t & 63;
  const int wv   = t >> 6;
  const int n0   = blockIdx.x * 2;

  // packed butterfly signs for the 6 lane stages: (+1,+1) or (-1,-1)
  unsigned sg[6];
  #pragma unroll
  for (int s = 0; s < 6; ++s)
    sg[s] = (lane & (1 << s)) ? 0xBC00BC00u : 0x3C003C00u;

  // load + scale + pack x once: elem e = c*1024 + t*4 + i (coalesced float4)
  const float S = 0.22272466f;   // cbrt(1/sqrt(8192)); S^3 = 0.011048543
  unsigned xp[4][4];
  {
    const float4* x0 = reinterpret_cast<const float4*>(x) + (size_t)n0 * (D_IN / 4);
    const float4* x1 = x0 + (D_IN / 4);
    #pragma unroll
    for (int c = 0; c < 4; ++c) {
      float4 a = x0[c * 256 + t];
      float4 b = x1[c * 256 + t];
      xp[c][0] = pkrtz(S * a.x, S * b.x);
      xp[c][1] = pkrtz(S * a.y, S * b.y);
      xp[c][2] = pkrtz(S * a.z, S * b.z);
      xp[c][3] = pkrtz(S * a.w, S * b.w);
    }
  }

  unsigned acc[32];
  #pragma unroll
  for (int k = 0; k < 32; ++k) acc[k] = 0x34003400u;   // f16x2(0.25, 0.25)

  uint4* z4 = reinterpret_cast<uint4*>(zp);

  #pragma unroll 1
  for (int d = 0; d < 3; ++d) {
    // ---- rad multiply (exact: rad = +-1 in f16) ----
    unsigned v[4][4];
    const float4* rrow = reinterpret_cast<const float4*>(rad) + d * (D_IN / 4);
    #pragma unroll
    for (int c = 0; c < 4; ++c) {
      float4 rv = rrow[c * 256 + t];
      v[c][0] = pmul(xp[c][0], pkrtz(rv.x, rv.x));
      v[c][1] = pmul(xp[c][1], pkrtz(rv.y, rv.y));
      v[c][2] = pmul(xp[c][2], pkrtz(rv.z, rv.z));
      v[c][3] = pmul(xp[c][3], pkrtz(rv.w, rv.w));
    }
    // bits {0,1}
    #pragma unroll
    for (int c = 0; c < 4; ++c) h4p(v[c][0], v[c][1], v[c][2], v[c][3]);
    // bits {10,11}
    #pragma unroll
    for (int i = 0; i < 4; ++i) h4p(v[0][i], v[1][i], v[2][i], v[3][i]);

    // ---- 6 packed lane stages ----
    #pragma unroll
    for (int c = 0; c < 4; ++c)
      #pragma unroll
      for (int i = 0; i < 4; ++i) {     // XOR 1 (e-bit 2)
        unsigned p = dppu<DPP_QUAD_XOR1>(v[c][i]);
        v[c][i] = pfma(sg[0], v[c][i], p);
      }
    #pragma unroll
    for (int c = 0; c < 4; ++c)
      #pragma unroll
      for (int i = 0; i < 4; ++i) {     // XOR 2 (e-bit 3)
        unsigned p = dppu<DPP_QUAD_XOR2>(v[c][i]);
        v[c][i] = pfma(sg[1], v[c][i], p);
      }
    #pragma unroll
    for (int c = 0; c < 4; ++c)
      #pragma unroll
      for (int i = 0; i < 4; ++i) {     // XOR 4 (e-bit 4): XOR7 then XOR3
        unsigned p = dppu<DPP_QUAD_XOR3>(dppu<DPP_ROW_HALF_MIRROR>(v[c][i]));
        v[c][i] = pfma(sg[2], v[c][i], p);
      }
    #pragma unroll
    for (int c = 0; c < 4; ++c)
      #pragma unroll
      for (int i = 0; i < 4; ++i) {     // XOR 8 (e-bit 5)
        unsigned p = dppu<DPP_ROW_ROR8>(v[c][i]);
        v[c][i] = pfma(sg[3], v[c][i], p);
      }
    #pragma unroll
    for (int c = 0; c < 4; ++c)
      #pragma unroll
      for (int i = 0; i < 4; ++i) {     // XOR 16 (e-bit 6)
#if __has_builtin(__builtin_amdgcn_permlane16_swap)
        auto r = __builtin_amdgcn_permlane16_swap(v[c][i], v[c][i], false, false);
        unsigned p = (lane & 16) ? (unsigned)r[0] : (unsigned)r[1];
#else
        unsigned p = (unsigned)__shfl_xor((int)v[c][i], 16, 64);
#endif
        v[c][i] = pfma(sg[4], v[c][i], p);
      }
    #pragma unroll
    for (int c = 0; c < 4; ++c)
      #pragma unroll
      for (int i = 0; i < 4; ++i) {     // XOR 32 (e-bit 7)
#if __has_builtin(__builtin_amdgcn_permlane32_swap)
        auto r = __builtin_amdgcn_permlane32_swap(v[c][i], v[c][i], false, false);
        unsigned p = (lane & 32) ? (unsigned)r[0] : (unsigned)r[1];
#else
        unsigned p = (unsigned)__shfl_xor((int)v[c][i], 32, 64);
#endif
        v[c][i] = pfma(sg[5], v[c][i], p);
      }

    __syncthreads();   // previous degree's gather has finished reading zp
    // ---- stage: natural-layout b128, conflict-free ----
    #pragma unroll
    for (int c = 0; c < 4; ++c) {
      uint4 u;
      u.x = v[c][0]; u.y = v[c][1]; u.z = v[c][2]; u.w = v[c][3];
      z4[c * 256 + t] = u;
    }
    __syncthreads();

    // ---- trip: bits {8,9}, packed h4p, disjoint per-thread b128 RMW ----
    {
      unsigned q[4][4];
      #pragma unroll
      for (int ww = 0; ww < 4; ++ww) {
        uint4 u = z4[wv * 256 + ww * 64 + lane];
        q[ww][0] = u.x; q[ww][1] = u.y; q[ww][2] = u.z; q[ww][3] = u.w;
      }
      #pragma unroll
      for (int i = 0; i < 4; ++i) h4p(q[0][i], q[1][i], q[2][i], q[3][i]);
      #pragma unroll
      for (int ww = 0; ww < 4; ++ww) {
        uint4 u;
        u.x = q[ww][0]; u.y = q[ww][1]; u.z = q[ww][2]; u.w = q[ww][3];
        z4[wv * 256 + ww * 64 + lane] = u;
      }
    }
    __syncthreads();

    // ---- packed gather: one u32 read + one pk_mul serves both rows ----
    const int4* p4 = reinterpret_cast<const int4*>(perm) + d * (D_F / 4);
    #pragma unroll
    for (int it = 0; it < 8; ++it) {
      int4 p = p4[it * 256 + t];
      acc[it*4+0] = pmul(acc[it*4+0], zp[p.x]);
      acc[it*4+1] = pmul(acc[it*4+1], zp[p.y]);
      acc[it*4+2] = pmul(acc[it*4+2], zp[p.z]);
      acc[it*4+3] = pmul(acc[it*4+3], zp[p.w]);
    }
  }

  // ---- coalesced float4 output, x4 undoes the 0.25 acc init ----
  float4* oa = reinterpret_cast<float4*>(out + (size_t)n0 * D_F);
  float4* ob = reinterpret_cast<float4*>(out + (size_t)(n0 + 1) * D_F);
  #pragma unroll
  for (int it = 0; it < 8; ++it) {
    float2 f0 = upk(acc[it*4+0]);
    float2 f1 = upk(acc[it*4+1]);
    float2 f2 = upk(acc[it*4+2]);
    float2 f3 = upk(acc[it*4+3]);
    oa[it * 256 + t] = make_float4(4.f*f0.x, 4.f*f1.x, 4.f*f2.x, 4.f*f3.x);
    ob[it * 256 + t] = make_float4(4.f*f0.y, 4.f*f1.y, 4.f*f2.y, 4.f*f3.y);
  }
}

extern "C" void kernel_launch(void* const* d_in, const int* in_sizes, int n_in,
                              void* d_out, int out_size, void* d_ws, size_t ws_size,
                              hipStream_t stream) {
  const float* x   = (const float*)d_in[0];
  const float* rad = (const float*)d_in[1];
  const int* perm  = (const int*)d_in[2];
  float* out       = (float*)d_out;
  srht_kernel<<<N_ROWS / 2, 256, 0, stream>>>(x, rad, perm, out);
}

// Round 11
// 82.867 us; speedup vs baseline: 1.6020x; 1.1103x over previous
//
#include <hip/hip_runtime.h>
#include <hip/hip_fp16.h>

#define N_ROWS 8192
#define D_IN   4096
#define D_F    8192

typedef float f32x4 __attribute__((ext_vector_type(4)));
typedef int   i32x4 __attribute__((ext_vector_type(4)));

// DPP move on a packed u32: result lane gets source lane per CTRL.
template<int CTRL>
__device__ __forceinline__ unsigned dppu(unsigned v) {
  int r = __builtin_amdgcn_update_dpp(0, (int)v, CTRL, 0xF, 0xF, true);
  return (unsigned)r;
}

#define DPP_QUAD_XOR1       0xB1   // quad_perm(1,0,3,2)
#define DPP_QUAD_XOR2       0x4E   // quad_perm(2,3,0,1)
#define DPP_QUAD_XOR3       0x1B   // quad_perm(3,2,1,0)
#define DPP_ROW_HALF_MIRROR 0x141  // XOR 7 within 16-lane row
#define DPP_ROW_ROR8        0x128  // rotate 8 within row == XOR 8

__device__ __forceinline__ unsigned pkrtz(float lo, float hi) {
#if __has_builtin(__builtin_amdgcn_cvt_pkrtz)
  auto h = __builtin_amdgcn_cvt_pkrtz(lo, hi);   // __fp16 ext_vector(2)
  return __builtin_bit_cast(unsigned, h);
#else
  __half2 h = __floats2half2_rn(lo, hi);
  return __builtin_bit_cast(unsigned, h);
#endif
}
__device__ __forceinline__ float2 upk(unsigned u) {
  return __half22float2(__builtin_bit_cast(__half2, u));
}
// packed f16x2 math on u32 bit patterns (v_pk_add/sub/mul/fma_f16)
__device__ __forceinline__ unsigned padd(unsigned a, unsigned b) {
  return __builtin_bit_cast(unsigned,
      __hadd2(__builtin_bit_cast(__half2, a), __builtin_bit_cast(__half2, b)));
}
__device__ __forceinline__ unsigned psub(unsigned a, unsigned b) {
  return __builtin_bit_cast(unsigned,
      __hsub2(__builtin_bit_cast(__half2, a), __builtin_bit_cast(__half2, b)));
}
__device__ __forceinline__ unsigned pmul(unsigned a, unsigned b) {
  return __builtin_bit_cast(unsigned,
      __hmul2(__builtin_bit_cast(__half2, a), __builtin_bit_cast(__half2, b)));
}
__device__ __forceinline__ unsigned pfma(unsigned a, unsigned b, unsigned c) {
  return __builtin_bit_cast(unsigned,
      __hfma2(__builtin_bit_cast(__half2, a), __builtin_bit_cast(__half2, b),
              __builtin_bit_cast(__half2, c)));
}
// packed radix-4 Hadamard butterfly
__device__ __forceinline__ void h4p(unsigned& a, unsigned& b,
                                    unsigned& c, unsigned& d) {
  unsigned t0 = padd(a, b), t1 = psub(a, b), t2 = padd(c, d), t3 = psub(c, d);
  a = padd(t0, t2); c = psub(t0, t2);
  b = padd(t1, t3); d = psub(t1, t3);
}

// One block = TWO rows packed as f16x2 in one u32 per element, END TO END
// (R10 structure). This round: VMEM<->compute overlap -
//  - first-half perm prefetched into regs BEFORE the stage barrier
//    (lands during stage+trip instead of stalling the gather)
//  - degree-2 gather fused with nontemporal output stores (spreads the
//    64 KB store burst across the gather phase)
//  - nontemporal x loads (zero reuse; keeps L2 for perm)
__global__ __launch_bounds__(256) void srht_kernel(
    const float* __restrict__ x,
    const float* __restrict__ rad,
    const int* __restrict__ perm,
    float* __restrict__ out)
{
  __shared__ __align__(16) unsigned zp[D_IN];   // 16 KiB packed f16x2
  const int t    = threadIdx.x;
  const int lane = t & 63;
  const int wv   = t >> 6;
  const int n0   = blockIdx.x * 2;

  // packed butterfly signs for the 6 lane stages: (+1,+1) or (-1,-1)
  unsigned sg[6];
  #pragma unroll
  for (int s = 0; s < 6; ++s)
    sg[s] = (lane & (1 << s)) ? 0xBC00BC00u : 0x3C003C00u;

  // load + scale + pack x once (nontemporal; elem e = c*1024 + t*4 + i)
  const float S = 0.22272466f;   // cbrt(1/sqrt(8192)); S^3 = 0.011048543
  unsigned xp[4][4];
  {
    const f32x4* x0 = reinterpret_cast<const f32x4*>(x) + (size_t)n0 * (D_IN / 4);
    const f32x4* x1 = x0 + (D_IN / 4);
    #pragma unroll
    for (int c = 0; c < 4; ++c) {
      f32x4 a = __builtin_nontemporal_load(x0 + c * 256 + t);
      f32x4 b = __builtin_nontemporal_load(x1 + c * 256 + t);
      xp[c][0] = pkrtz(S * a[0], S * b[0]);
      xp[c][1] = pkrtz(S * a[1], S * b[1]);
      xp[c][2] = pkrtz(S * a[2], S * b[2]);
      xp[c][3] = pkrtz(S * a[3], S * b[3]);
    }
  }

  unsigned acc[32];
  #pragma unroll
  for (int k = 0; k < 32; ++k) acc[k] = 0x34003400u;   // f16x2(0.25, 0.25)

  uint4* z4 = reinterpret_cast<uint4*>(zp);

  // FWHT degree d: rad-mul, reg h4p (bits {0,1},{10,11}), 6 packed lane
  // stages (bits {2..7}), prefetch first-half perm, stage, trip (bits {8,9}).
  // Leaves zp gather-ready (barrier included).
  auto fwht_stage_trip = [&](int d, i32x4* pp) {
    unsigned v[4][4];
    const f32x4* rrow = reinterpret_cast<const f32x4*>(rad) + d * (D_IN / 4);
    #pragma unroll
    for (int c = 0; c < 4; ++c) {
      f32x4 rv = rrow[c * 256 + t];
      v[c][0] = pmul(xp[c][0], pkrtz(rv[0], rv[0]));
      v[c][1] = pmul(xp[c][1], pkrtz(rv[1], rv[1]));
      v[c][2] = pmul(xp[c][2], pkrtz(rv[2], rv[2]));
      v[c][3] = pmul(xp[c][3], pkrtz(rv[3], rv[3]));
    }
    #pragma unroll
    for (int c = 0; c < 4; ++c) h4p(v[c][0], v[c][1], v[c][2], v[c][3]);
    #pragma unroll
    for (int i = 0; i < 4; ++i) h4p(v[0][i], v[1][i], v[2][i], v[3][i]);

    #pragma unroll
    for (int c = 0; c < 4; ++c)
      #pragma unroll
      for (int i = 0; i < 4; ++i) {     // XOR 1 (e-bit 2)
        unsigned p = dppu<DPP_QUAD_XOR1>(v[c][i]);
        v[c][i] = pfma(sg[0], v[c][i], p);
      }
    #pragma unroll
    for (int c = 0; c < 4; ++c)
      #pragma unroll
      for (int i = 0; i < 4; ++i) {     // XOR 2 (e-bit 3)
        unsigned p = dppu<DPP_QUAD_XOR2>(v[c][i]);
        v[c][i] = pfma(sg[1], v[c][i], p);
      }
    #pragma unroll
    for (int c = 0; c < 4; ++c)
      #pragma unroll
      for (int i = 0; i < 4; ++i) {     // XOR 4 (e-bit 4): XOR7 then XOR3
        unsigned p = dppu<DPP_QUAD_XOR3>(dppu<DPP_ROW_HALF_MIRROR>(v[c][i]));
        v[c][i] = pfma(sg[2], v[c][i], p);
      }
    #pragma unroll
    for (int c = 0; c < 4; ++c)
      #pragma unroll
      for (int i = 0; i < 4; ++i) {     // XOR 8 (e-bit 5)
        unsigned p = dppu<DPP_ROW_ROR8>(v[c][i]);
        v[c][i] = pfma(sg[3], v[c][i], p);
      }
    #pragma unroll
    for (int c = 0; c < 4; ++c)
      #pragma unroll
      for (int i = 0; i < 4; ++i) {     // XOR 16 (e-bit 6)
#if __has_builtin(__builtin_amdgcn_permlane16_swap)
        auto r = __builtin_amdgcn_permlane16_swap(v[c][i], v[c][i], false, false);
        unsigned p = (lane & 16) ? (unsigned)r[0] : (unsigned)r[1];
#else
        unsigned p = (unsigned)__shfl_xor((int)v[c][i], 16, 64);
#endif
        v[c][i] = pfma(sg[4], v[c][i], p);
      }
    #pragma unroll
    for (int c = 0; c < 4; ++c)
      #pragma unroll
      for (int i = 0; i < 4; ++i) {     // XOR 32 (e-bit 7)
#if __has_builtin(__builtin_amdgcn_permlane32_swap)
        auto r = __builtin_amdgcn_permlane32_swap(v[c][i], v[c][i], false, false);
        unsigned p = (lane & 32) ? (unsigned)r[0] : (unsigned)r[1];
#else
        unsigned p = (unsigned)__shfl_xor((int)v[c][i], 32, 64);
#endif
        v[c][i] = pfma(sg[5], v[c][i], p);
      }

    // prefetch first-half perm: lands during stage+trip (2 barriers of slack)
    const i32x4* p4 = reinterpret_cast<const i32x4*>(perm) + d * (D_F / 4);
    pp[0] = p4[0 * 256 + t];
    pp[1] = p4[1 * 256 + t];
    pp[2] = p4[2 * 256 + t];
    pp[3] = p4[3 * 256 + t];

    __syncthreads();   // previous degree's gather has finished reading zp
    #pragma unroll
    for (int c = 0; c < 4; ++c) {
      uint4 u;
      u.x = v[c][0]; u.y = v[c][1]; u.z = v[c][2]; u.w = v[c][3];
      z4[c * 256 + t] = u;
    }
    __syncthreads();

    {   // trip: bits {8,9}, packed h4p, disjoint per-thread b128 RMW
      unsigned q[4][4];
      #pragma unroll
      for (int ww = 0; ww < 4; ++ww) {
        uint4 u = z4[wv * 256 + ww * 64 + lane];
        q[ww][0] = u.x; q[ww][1] = u.y; q[ww][2] = u.z; q[ww][3] = u.w;
      }
      #pragma unroll
      for (int i = 0; i < 4; ++i) h4p(q[0][i], q[1][i], q[2][i], q[3][i]);
      #pragma unroll
      for (int ww = 0; ww < 4; ++ww) {
        uint4 u;
        u.x = q[ww][0]; u.y = q[ww][1]; u.z = q[ww][2]; u.w = q[ww][3];
        z4[wv * 256 + ww * 64 + lane] = u;
      }
    }
    __syncthreads();
  };

  // ---- degrees 0,1: gather into packed acc ----
  #pragma unroll 1
  for (int d = 0; d < 2; ++d) {
    i32x4 pp[4];
    fwht_stage_trip(d, pp);
    const i32x4* p4 = reinterpret_cast<const i32x4*>(perm) + d * (D_F / 4);
    #pragma unroll
    for (int it = 0; it < 8; ++it) {
      i32x4 p = (it < 4) ? pp[it] : p4[it * 256 + t];
      acc[it*4+0] = pmul(acc[it*4+0], zp[p[0]]);
      acc[it*4+1] = pmul(acc[it*4+1], zp[p[1]]);
      acc[it*4+2] = pmul(acc[it*4+2], zp[p[2]]);
      acc[it*4+3] = pmul(acc[it*4+3], zp[p[3]]);
    }
  }

  // ---- degree 2: gather fused with nontemporal output stores ----
  {
    i32x4 pp[4];
    fwht_stage_trip(2, pp);
    const i32x4* p4 = reinterpret_cast<const i32x4*>(perm) + 2 * (D_F / 4);
    f32x4* oa = reinterpret_cast<f32x4*>(out + (size_t)n0 * D_F);
    f32x4* ob = reinterpret_cast<f32x4*>(out + (size_t)(n0 + 1) * D_F);
    #pragma unroll
    for (int it = 0; it < 8; ++it) {
      i32x4 p = (it < 4) ? pp[it] : p4[it * 256 + t];
      unsigned a0 = pmul(acc[it*4+0], zp[p[0]]);
      unsigned a1 = pmul(acc[it*4+1], zp[p[1]]);
      unsigned a2 = pmul(acc[it*4+2], zp[p[2]]);
      unsigned a3 = pmul(acc[it*4+3], zp[p[3]]);
      float2 f0 = upk(a0), f1 = upk(a1), f2 = upk(a2), f3 = upk(a3);
      f32x4 va = {4.f * f0.x, 4.f * f1.x, 4.f * f2.x, 4.f * f3.x};
      f32x4 vb = {4.f * f0.y, 4.f * f1.y, 4.f * f2.y, 4.f * f3.y};
      __builtin_nontemporal_store(va, oa + it * 256 + t);
      __builtin_nontemporal_store(vb, ob + it * 256 + t);
    }
  }
}

extern "C" void kernel_launch(void* const* d_in, const int* in_sizes, int n_in,
                              void* d_out, int out_size, void* d_ws, size_t ws_size,
                              hipStream_t stream) {
  const float* x   = (const float*)d_in[0];
  const float* rad = (const float*)d_in[1];
  const int* perm  = (const int*)d_in[2];
  float* out       = (float*)d_out;
  srht_kernel<<<N_ROWS / 2, 256, 0, stream>>>(x, rad, perm, out);
}